// Round 1
// baseline (197.989 us; speedup 1.0000x reference)
//
#include <hip/hip_runtime.h>
#include <hip/hip_bf16.h>

// QFD loss: out = 0.1 * sum_b diff_b^T A diff_b, A_ij = 1 - |i-j|/85.
// Identity: q = S^2 - (2/85) * (S*sumL - sumL2), where
//   S = sum_i d_i, L_k = prefix sum, sumL = sum_{k<D-1} L_k, sumL2 = sum_{k<D-1} L_k^2.
// O(D) per row -> purely memory-bound (178 MB read, ~28 us floor).

#define QFD_D 85
#define ROWS_PER_BLOCK 128
#define THREADS 256

__global__ __launch_bounds__(THREADS) void qfd_kernel(
    const float* __restrict__ in, const float* __restrict__ tgt,
    float* __restrict__ out) {
    // 128 rows * 85 floats = 43,520 B of LDS (3 blocks/CU -> 12 waves/CU)
    __shared__ float diff[ROWS_PER_BLOCK * QFD_D];
    __shared__ float wsum[THREADS / 64];

    const int tid = threadIdx.x;
    const int E = ROWS_PER_BLOCK * QFD_D;      // 10880 floats per block
    const int base = blockIdx.x * E;           // max 22,282,240 -> fits int32

    // ---- Stage |in - tgt| into LDS, coalesced float4 (base*4 % 16 == 0) ----
    const float4* in4 = reinterpret_cast<const float4*>(in + base);
    const float4* tg4 = reinterpret_cast<const float4*>(tgt + base);
    float4* df4 = reinterpret_cast<float4*>(diff);
    for (int idx = tid; idx < E / 4; idx += THREADS) {  // 2720 float4s
        float4 a = in4[idx];
        float4 b = tg4[idx];
        float4 r;
        r.x = fabsf(a.x - b.x);
        r.y = fabsf(a.y - b.y);
        r.z = fabsf(a.z - b.z);
        r.w = fabsf(a.w - b.w);
        df4[idx] = r;
    }
    __syncthreads();

    // ---- Per-row sequential scan (threads 0..127; stride 85 -> bank stride
    // 21, coprime with 32 -> only 2-way lane aliasing = free) ----
    float q = 0.0f;
    if (tid < ROWS_PER_BLOCK) {
        const float* d = &diff[tid * QFD_D];
        float L = 0.0f, sumL = 0.0f, sumL2 = 0.0f;
        #pragma unroll 4
        for (int k = 0; k < QFD_D - 1; ++k) {
            L += d[k];
            sumL += L;
            sumL2 = fmaf(L, L, sumL2);
        }
        const float S = L + d[QFD_D - 1];
        q = fmaf(S, S, -(2.0f / 85.0f) * (S * sumL - sumL2));
    }

    // ---- Block reduction: wave shuffle -> LDS -> one atomicAdd/block ----
    #pragma unroll
    for (int off = 32; off > 0; off >>= 1)
        q += __shfl_down(q, off, 64);
    if ((tid & 63) == 0) wsum[tid >> 6] = q;
    __syncthreads();
    if (tid == 0) {
        float s = 0.0f;
        #pragma unroll
        for (int w = 0; w < THREADS / 64; ++w) s += wsum[w];
        atomicAdd(out, 0.1f * s);
    }
}

extern "C" void kernel_launch(void* const* d_in, const int* in_sizes, int n_in,
                              void* d_out, int out_size, void* d_ws, size_t ws_size,
                              hipStream_t stream) {
    const float* in  = (const float*)d_in[0];
    const float* tgt = (const float*)d_in[1];
    float* out = (float*)d_out;

    const int B = in_sizes[0] / QFD_D;         // 262144
    const int grid = B / ROWS_PER_BLOCK;       // 2048 blocks

    // d_out is re-poisoned to 0xAA before every timed launch; zero it here
    // (hipMemsetAsync is graph-capturable).
    hipMemsetAsync(d_out, 0, sizeof(float), stream);
    qfd_kernel<<<grid, THREADS, 0, stream>>>(in, tgt, out);
}